// Round 1
// 461.788 us; speedup vs baseline: 1.0065x; 1.0065x over previous
//
#include <hip/hip_runtime.h>
#include <cstdint>

// Fused ConvTranspose2d(stride1,crop) + tanh-GELU + per-pixel GroupNorm(8 groups)
// N=32, Cin=64, Cout=128, H=W=128, K=3.
// Implicit GEMM: one block per (n, oh): C[ow=128][oc=128] = A[ow][k=576] * B[k][oc],
// k = (kh*3+kw)*64 + ic, A[ow][k] = x[n, ic, oh-kh, ow-kw] (zero-padded low side).
// bf16 MFMA 16x16x32, fp32 accumulate. GroupNorm group = 16 oc = one MFMA n-tile.
//
// This revision (vs 2-block/CU baseline at 210us):
//  - B fragments loaded straight from L2-resident BT into registers (double-
//    buffered 1 k-step ahead) -> no Bs LDS, K-loop is BARRIER-FREE (18 syncs -> 1).
//  - xs re-packed [wpos 130][3r*64ic + 8pad] (400B row, mod128=16 -> optimal
//    8-lane/16B-column bank spread on both stage writes and fragment reads).
//  - epilogue split into two 64-oc halves (4 GN groups each, half == wx).
//  - static LDS 75776 -> 52000 B => 3 blocks/CU (12 waves), launch_bounds(256,3).
//  - bijective XCD swizzle: consecutive oh (sharing 2/3 x rows) on same XCD L2.

#define NG 8
#define EPS 1e-5f

typedef __attribute__((ext_vector_type(8))) short bf16x8;
typedef __attribute__((ext_vector_type(4))) float f32x4;
typedef __attribute__((ext_vector_type(4))) unsigned int u32x4;

// GEMM phase : xs[wpos 0..129][r 0..2][ic 0..63] bf16, row stride XSW=200 shorts
//              (3*64=192 data + 8 pad; 400B row: 16B-aligned, mod 128B = 16).
// Epilogue   : tile[64 oc][132 ow-padded] f32 = 33792 B @0
//              mean[4][128], rstd[4][128] f32 =  4096 B @33792
#define XSW 200
#define XS_BYTES (130 * XSW * 2)            // 52000
#define TILE_STRIDE 132
#define STAT_OFF (64 * TILE_STRIDE * 4)     // 33792
#define EPI_BYTES (STAT_OFF + 2 * 4 * 128 * 4)  // 37888
#define SMEM_BYTES XS_BYTES                 // 52000 >= 37888; 3 per CU fits 160K

static_assert(SMEM_BYTES >= EPI_BYTES, "epilogue overlay must fit");

__device__ inline unsigned short f2bf(float f) {   // RTNE fp32->bf16
  unsigned int u = __float_as_uint(f);
  return (unsigned short)((u + 0x7fffu + ((u >> 16) & 1u)) >> 16);
}

__device__ inline float gelu_f(float y) {
  // 0.5*y*(1+tanh(0.7978845608*(y+0.044715*y^3))); tanh(u)=1-2/(exp(2u)+1)
  float u = 0.7978845608f * (y + 0.044715f * y * y * y);
  float e = __expf(2.0f * u);
  float t = 1.0f - 2.0f * __builtin_amdgcn_rcpf(e + 1.0f);
  return 0.5f * y * (1.0f + t);
}

// Pre-block weights: BT[kk=18][oc=128][k31=32] bf16, global k = kk*32+k31 = tap*64+ic
__global__ void prep_w(const float* __restrict__ w, unsigned short* __restrict__ BT) {
  int idx = blockIdx.x * 256 + threadIdx.x;   // 73728 total
  int k31 = idx & 31;
  int oc  = (idx >> 5) & 127;
  int kk  = idx >> 12;
  int k   = kk * 32 + k31;
  int t   = k >> 6;          // tap = kh*3+kw
  int ic  = k & 63;
  BT[idx] = f2bf(w[(ic * 128 + oc) * 9 + t]);
}

__global__ __launch_bounds__(256, 3)
void conv_gelu_gn(const float* __restrict__ x,
                  const unsigned short* __restrict__ BT,
                  const float* __restrict__ bias,
                  const float* __restrict__ gnw,
                  const float* __restrict__ gnb,
                  float* __restrict__ out) {
  __shared__ __align__(16) unsigned char smem[SMEM_BYTES];
  unsigned short* xs    = (unsigned short*)smem;
  float*          tile  = (float*)smem;
  float*          meanA = (float*)(smem + STAT_OFF);
  float*          rstdA = meanA + 4 * 128;

  const int tid = threadIdx.x;
  // Bijective XCD swizzle: 4096 wgs, 8 XCDs, 512 each; oh-contiguous per XCD so
  // neighboring oh blocks (sharing 2 of 3 x rows) hit the same XCD L2.
  const int flat = blockIdx.y * 128 + blockIdx.x;
  const int nf   = (flat & 7) * 512 + (flat >> 3);
  const int oh   = nf & 127, n = nf >> 7;

  const int lane = tid & 63, wave = tid >> 6;
  const int wy   = wave >> 1, wx = wave & 1;   // wave tile: [wy*64 ow][wx*64 oc]
  const int cl   = lane & 15, q = lane >> 4;

  // ---- stage A: x rows oh-2..oh -> xs[wpos][r][ic] bf16, wpos=w+2, wpos<2 zero
  {
    int w_  = tid & 127;
    int icq = tid >> 7;                 // wave-uniform
    #pragma unroll
    for (int rep = 0; rep < 12; ++rep) {
      int slot = rep * 2 + icq;         // 0..23 = (r 0..2) x (ic8 0..7)
      int r = slot >> 3;
      int ic0 = (slot & 7) * 8;
      int h = oh - 2 + r;
      u32x4 pk;
      if (h >= 0) {
        const float* src = x + (((n * 64 + ic0) * 128 + h) * 128) + w_;
        float v0 = src[0],         v1 = src[16384],     v2 = src[2 * 16384], v3 = src[3 * 16384];
        float v4 = src[4 * 16384], v5 = src[5 * 16384], v6 = src[6 * 16384], v7 = src[7 * 16384];
        pk.x = (unsigned)f2bf(v0) | ((unsigned)f2bf(v1) << 16);
        pk.y = (unsigned)f2bf(v2) | ((unsigned)f2bf(v3) << 16);
        pk.z = (unsigned)f2bf(v4) | ((unsigned)f2bf(v5) << 16);
        pk.w = (unsigned)f2bf(v6) | ((unsigned)f2bf(v7) << 16);
      } else {
        pk.x = pk.y = pk.z = pk.w = 0u;
      }
      *(u32x4*)(xs + (2 + w_) * XSW + r * 64 + ic0) = pk;
      if (w_ < 2) {                     // left zero pad (wpos 0,1)
        u32x4 z; z.x = z.y = z.z = z.w = 0u;
        *(u32x4*)(xs + w_ * XSW + r * 64 + ic0) = z;
      }
    }
  }

  // ---- B fragments straight from global (BT is L2-resident: 147KB x 4096 blocks).
  // Per k-step each wave needs B[32k][64oc] = exactly its 4 fragments; coalesced
  // 16B/lane. Double-buffered in registers one step ahead.
  const int boffBase = (wx * 64 + cl) * 32 + q * 8;
  const unsigned short* Bg = BT + boffBase;

  auto loadB = [&](int kk, bf16x8& b0, bf16x8& b1, bf16x8& b2, bf16x8& b3) {
    const unsigned short* bx = Bg + kk * 4096;
    b0 = *(const bf16x8*)(bx);
    b1 = *(const bf16x8*)(bx + 512);
    b2 = *(const bf16x8*)(bx + 1024);
    b3 = *(const bf16x8*)(bx + 1536);
  };

  f32x4 acc[4][4] = {};
  const int arowBase = wy * 64 + cl + 2;

  auto step = [&](int kk, const bf16x8& b0, const bf16x8& b1,
                  const bf16x8& b2, const bf16x8& b3) {
    int t = kk >> 1;
    int kh = t / 3, kw = t - 3 * kh;
    int icb = (kk & 1) * 32;
    const unsigned short* ax = xs + (arowBase - kw) * XSW + (2 - kh) * 64 + icb + q * 8;
    bf16x8 a0 = *(const bf16x8*)(ax);
    bf16x8 a1 = *(const bf16x8*)(ax + 16 * XSW);
    bf16x8 a2 = *(const bf16x8*)(ax + 32 * XSW);
    bf16x8 a3 = *(const bf16x8*)(ax + 48 * XSW);
    acc[0][0] = __builtin_amdgcn_mfma_f32_16x16x32_bf16(a0, b0, acc[0][0], 0, 0, 0);
    acc[0][1] = __builtin_amdgcn_mfma_f32_16x16x32_bf16(a0, b1, acc[0][1], 0, 0, 0);
    acc[0][2] = __builtin_amdgcn_mfma_f32_16x16x32_bf16(a0, b2, acc[0][2], 0, 0, 0);
    acc[0][3] = __builtin_amdgcn_mfma_f32_16x16x32_bf16(a0, b3, acc[0][3], 0, 0, 0);
    acc[1][0] = __builtin_amdgcn_mfma_f32_16x16x32_bf16(a1, b0, acc[1][0], 0, 0, 0);
    acc[1][1] = __builtin_amdgcn_mfma_f32_16x16x32_bf16(a1, b1, acc[1][1], 0, 0, 0);
    acc[1][2] = __builtin_amdgcn_mfma_f32_16x16x32_bf16(a1, b2, acc[1][2], 0, 0, 0);
    acc[1][3] = __builtin_amdgcn_mfma_f32_16x16x32_bf16(a1, b3, acc[1][3], 0, 0, 0);
    acc[2][0] = __builtin_amdgcn_mfma_f32_16x16x32_bf16(a2, b0, acc[2][0], 0, 0, 0);
    acc[2][1] = __builtin_amdgcn_mfma_f32_16x16x32_bf16(a2, b1, acc[2][1], 0, 0, 0);
    acc[2][2] = __builtin_amdgcn_mfma_f32_16x16x32_bf16(a2, b2, acc[2][2], 0, 0, 0);
    acc[2][3] = __builtin_amdgcn_mfma_f32_16x16x32_bf16(a2, b3, acc[2][3], 0, 0, 0);
    acc[3][0] = __builtin_amdgcn_mfma_f32_16x16x32_bf16(a3, b0, acc[3][0], 0, 0, 0);
    acc[3][1] = __builtin_amdgcn_mfma_f32_16x16x32_bf16(a3, b1, acc[3][1], 0, 0, 0);
    acc[3][2] = __builtin_amdgcn_mfma_f32_16x16x32_bf16(a3, b2, acc[3][2], 0, 0, 0);
    acc[3][3] = __builtin_amdgcn_mfma_f32_16x16x32_bf16(a3, b3, acc[3][3], 0, 0, 0);
  };

  bf16x8 pb0, pb1, pb2, pb3, nb0, nb1, nb2, nb3;
  loadB(0, pb0, pb1, pb2, pb3);      // issue before the stage barrier

  __syncthreads();                   // xs staged; only barrier before epilogue

  #pragma unroll
  for (int kp = 0; kp < 9; ++kp) {
    loadB(2 * kp + 1, nb0, nb1, nb2, nb3);
    step(2 * kp, pb0, pb1, pb2, pb3);
    if (kp < 8) loadB(2 * kp + 2, pb0, pb1, pb2, pb3);
    step(2 * kp + 1, nb0, nb1, nb2, nb3);
  }

  // ---- epilogue: bias + GELU in regs (all waves), then two 64-oc halves
  float bj[4];
  #pragma unroll
  for (int j = 0; j < 4; ++j) bj[j] = bias[wx * 64 + j * 16 + cl];

  #pragma unroll
  for (int i = 0; i < 4; ++i)
    #pragma unroll
    for (int j = 0; j < 4; ++j)
      #pragma unroll
      for (int r = 0; r < 4; ++r)
        acc[i][j][r] = gelu_f(acc[i][j][r] + bj[j]);

  __syncthreads();   // all xs reads done before tile overlays it

  #pragma unroll 1
  for (int half = 0; half < 2; ++half) {
    // acc -> tile for this oc half (oc half == wx by construction)
    if (wx == half) {
      #pragma unroll
      for (int i = 0; i < 4; ++i) {
        int owb = wy * 64 + i * 16 + q * 4;     // D row = ow = q*4+reg
        #pragma unroll
        for (int j = 0; j < 4; ++j)
          *(f32x4*)(tile + (j * 16 + cl) * TILE_STRIDE + owb) = acc[i][j];
      }
    }
    __syncthreads();

    // per-pixel group stats: 4 local groups x 128 ow
    #pragma unroll
    for (int s = tid; s < 4 * 128; s += 256) {
      int gl = s >> 7, ow = s & 127;
      const float* p = tile + (gl * 16) * TILE_STRIDE + ow;
      float sum = 0.f, s2 = 0.f;
      #pragma unroll
      for (int k = 0; k < 16; ++k) {
        float v = p[k * TILE_STRIDE];
        sum += v; s2 += v * v;
      }
      float mean = sum * (1.f / 16.f);
      float var  = s2 * (1.f / 16.f) - mean * mean;
      meanA[s] = mean;
      rstdA[s] = __builtin_amdgcn_rsqf(var + EPS);
    }
    __syncthreads();

    // normalize + affine + coalesced store (64 oc x 128 ow)
    #pragma unroll 4
    for (int it = 0; it < 8; ++it) {
      int idx = it * 256 + tid;
      int ow4 = (idx & 31) * 4;
      int ocl = idx >> 5;               // 0..63
      int oc  = half * 64 + ocl;
      int gl  = ocl >> 4;
      float gw = gnw[oc], gb = gnb[oc];
      f32x4 v  = *(const f32x4*)(tile + ocl * TILE_STRIDE + ow4);
      f32x4 m4 = *(const f32x4*)(meanA + gl * 128 + ow4);
      f32x4 r4 = *(const f32x4*)(rstdA + gl * 128 + ow4);
      f32x4 o;
      #pragma unroll
      for (int r = 0; r < 4; ++r) o[r] = (v[r] - m4[r]) * r4[r] * gw + gb;
      *(f32x4*)(out + ((n * 128 + oc) * 128 + oh) * 128 + ow4) = o;
    }
    if (half == 0) __syncthreads();   // tile/stats reads done before half 1 writes
  }
}

extern "C" void kernel_launch(void* const* d_in, const int* in_sizes, int n_in,
                              void* d_out, int out_size, void* d_ws, size_t ws_size,
                              hipStream_t stream) {
  const float* x   = (const float*)d_in[0];
  const float* w   = (const float*)d_in[1];
  const float* b   = (const float*)d_in[2];
  const float* gnw = (const float*)d_in[3];
  const float* gnb = (const float*)d_in[4];
  float* out = (float*)d_out;
  unsigned short* BT = (unsigned short*)d_ws;   // 18*128*32 bf16 = 147456 B

  prep_w<<<288, 256, 0, stream>>>(w, BT);
  conv_gelu_gn<<<dim3(128, 32), 256, 0, stream>>>(x, BT, b, gnw, gnb, out);
}

// Round 2
// 454.880 us; speedup vs baseline: 1.0218x; 1.0152x over previous
//
#include <hip/hip_runtime.h>
#include <cstdint>

// Fused ConvTranspose2d(stride1,crop) + tanh-GELU + per-pixel GroupNorm(8 groups)
// N=32, Cin=64, Cout=128, H=W=128, K=3.
// Implicit GEMM: one block per (n, oh): C[ow=128][oc=128] = A[ow][k=576] * B[k][oc],
// k = (kh*3+kw)*64 + ic, A[ow][k] = x[n, ic, oh-kh, ow-kw] (zero-padded low side).
// bf16 MFMA 16x16x32, fp32 accumulate. GroupNorm group = 16 oc = one MFMA n-tile.
//
// R2 changes (vs R1 203us, MfmaUtil 16%, all pipes low => latency-bound in-wave):
//  - Software pipeline deepened: A-fragments prefetched 1 k-step ahead (ds_read
//    ~120cy), B-fragments 2 k-steps ahead via 3-buffer register rotation
//    (L2 ~200-400cy). 18 steps fully unrolled (period-6 rotation x3) so every
//    buffer index is static.
//  - Staging f32->bf16 via v_cvt_pk_bf16_f32 (1 inst / 2 values) instead of
//    4-op manual RTNE: ~600 VALU insts/thread removed.
//  - s_setprio(1) around each pure-MFMA cluster (waves drift => role diversity).

#define NG 8
#define EPS 1e-5f

typedef __attribute__((ext_vector_type(8))) short bf16x8;
typedef __attribute__((ext_vector_type(4))) float f32x4;
typedef __attribute__((ext_vector_type(4))) unsigned int u32x4;

// GEMM phase : xs[wpos 0..129][r 0..2][ic 0..63] bf16, row stride XSW=200 shorts
//              (3*64=192 data + 8 pad; 400B row: 16B-aligned, mod 128B = 16).
// Epilogue   : tile[64 oc][132 ow-padded] f32 = 33792 B @0
//              mean[4][128], rstd[4][128] f32 =  4096 B @33792
#define XSW 200
#define XS_BYTES (130 * XSW * 2)            // 52000
#define TILE_STRIDE 132
#define STAT_OFF (64 * TILE_STRIDE * 4)     // 33792
#define EPI_BYTES (STAT_OFF + 2 * 4 * 128 * 4)  // 37888
#define SMEM_BYTES XS_BYTES                 // 52000 >= 37888; 3 blocks/CU

static_assert(SMEM_BYTES >= EPI_BYTES, "epilogue overlay must fit");

__device__ inline unsigned short f2bf(float f) {   // RTNE fp32->bf16 (host-prep only path)
  unsigned int u = __float_as_uint(f);
  return (unsigned short)((u + 0x7fffu + ((u >> 16) & 1u)) >> 16);
}

__device__ inline unsigned cvt_pk_bf16(float lo, float hi) {  // RTNE, 1 inst
  unsigned r;
  asm("v_cvt_pk_bf16_f32 %0, %1, %2" : "=v"(r) : "v"(lo), "v"(hi));
  return r;
}

__device__ inline float gelu_f(float y) {
  // 0.5*y*(1+tanh(0.7978845608*(y+0.044715*y^3))); tanh(u)=1-2/(exp(2u)+1)
  float u = 0.7978845608f * (y + 0.044715f * y * y * y);
  float e = __expf(2.0f * u);
  float t = 1.0f - 2.0f * __builtin_amdgcn_rcpf(e + 1.0f);
  return 0.5f * y * (1.0f + t);
}

// Pre-block weights: BT[kk=18][oc=128][k31=32] bf16, global k = kk*32+k31 = tap*64+ic
__global__ void prep_w(const float* __restrict__ w, unsigned short* __restrict__ BT) {
  int idx = blockIdx.x * 256 + threadIdx.x;   // 73728 total
  int k31 = idx & 31;
  int oc  = (idx >> 5) & 127;
  int kk  = idx >> 12;
  int k   = kk * 32 + k31;
  int t   = k >> 6;          // tap = kh*3+kw
  int ic  = k & 63;
  BT[idx] = f2bf(w[(ic * 128 + oc) * 9 + t]);
}

struct Afrag { bf16x8 a0, a1, a2, a3; };
struct Bfrag { bf16x8 b0, b1, b2, b3; };

__global__ __launch_bounds__(256, 3)
void conv_gelu_gn(const float* __restrict__ x,
                  const unsigned short* __restrict__ BT,
                  const float* __restrict__ bias,
                  const float* __restrict__ gnw,
                  const float* __restrict__ gnb,
                  float* __restrict__ out) {
  __shared__ __align__(16) unsigned char smem[SMEM_BYTES];
  unsigned short* xs    = (unsigned short*)smem;
  float*          tile  = (float*)smem;
  float*          meanA = (float*)(smem + STAT_OFF);
  float*          rstdA = meanA + 4 * 128;

  const int tid = threadIdx.x;
  // Bijective XCD swizzle: 4096 wgs, 8 XCDs, 512 each; oh-contiguous per XCD so
  // neighboring oh blocks (sharing 2 of 3 x rows) hit the same XCD L2.
  const int flat = blockIdx.y * 128 + blockIdx.x;
  const int nf   = (flat & 7) * 512 + (flat >> 3);
  const int oh   = nf & 127, n = nf >> 7;

  const int lane = tid & 63, wave = tid >> 6;
  const int wy   = wave >> 1, wx = wave & 1;   // wave tile: [wy*64 ow][wx*64 oc]
  const int cl   = lane & 15, q = lane >> 4;

  // ---- B fragments straight from global (BT is L2-resident: 147KB x 4096 blocks).
  const int boffBase = (wx * 64 + cl) * 32 + q * 8;
  const unsigned short* Bg = BT + boffBase;

  auto loadB = [&](int kk, Bfrag& B) {
    int kkc = kk > 17 ? 17 : kk;        // static after unroll
    const unsigned short* bx = Bg + kkc * 4096;
    B.b0 = *(const bf16x8*)(bx);
    B.b1 = *(const bf16x8*)(bx + 512);
    B.b2 = *(const bf16x8*)(bx + 1024);
    B.b3 = *(const bf16x8*)(bx + 1536);
  };

  Bfrag B0, B1, B2;
  loadB(0, B0);                          // in flight across the whole staging phase
  loadB(1, B1);

  // ---- stage A: x rows oh-2..oh -> xs[wpos][r][ic] bf16, wpos=w+2, wpos<2 zero
  {
    int w_  = tid & 127;
    int icq = tid >> 7;                 // wave-uniform
    #pragma unroll
    for (int rep = 0; rep < 12; ++rep) {
      int slot = rep * 2 + icq;         // 0..23 = (r 0..2) x (ic8 0..7)
      int r = slot >> 3;
      int ic0 = (slot & 7) * 8;
      int h = oh - 2 + r;
      u32x4 pk;
      if (h >= 0) {
        const float* src = x + (((n * 64 + ic0) * 128 + h) * 128) + w_;
        float v0 = src[0],         v1 = src[16384],     v2 = src[2 * 16384], v3 = src[3 * 16384];
        float v4 = src[4 * 16384], v5 = src[5 * 16384], v6 = src[6 * 16384], v7 = src[7 * 16384];
        pk.x = cvt_pk_bf16(v0, v1);
        pk.y = cvt_pk_bf16(v2, v3);
        pk.z = cvt_pk_bf16(v4, v5);
        pk.w = cvt_pk_bf16(v6, v7);
      } else {
        pk.x = pk.y = pk.z = pk.w = 0u;
      }
      *(u32x4*)(xs + (2 + w_) * XSW + r * 64 + ic0) = pk;
      if (w_ < 2) {                     // left zero pad (wpos 0,1)
        u32x4 z; z.x = z.y = z.z = z.w = 0u;
        *(u32x4*)(xs + w_ * XSW + r * 64 + ic0) = z;
      }
    }
  }

  f32x4 acc[4][4] = {};
  const int arowBase = wy * 64 + cl + 2;

  auto ldA = [&](int kk, Afrag& A) {
    int kkc = kk > 17 ? 17 : kk;        // static after unroll
    int t = kkc >> 1;
    int kh = t / 3, kw = t - 3 * kh;
    int icb = (kkc & 1) * 32;
    const unsigned short* ax = xs + (arowBase - kw) * XSW + (2 - kh) * 64 + icb + q * 8;
    A.a0 = *(const bf16x8*)(ax);
    A.a1 = *(const bf16x8*)(ax + 16 * XSW);
    A.a2 = *(const bf16x8*)(ax + 32 * XSW);
    A.a3 = *(const bf16x8*)(ax + 48 * XSW);
  };

  auto mm = [&](const Afrag& A, const Bfrag& B) {
    __builtin_amdgcn_s_setprio(1);
    acc[0][0] = __builtin_amdgcn_mfma_f32_16x16x32_bf16(A.a0, B.b0, acc[0][0], 0, 0, 0);
    acc[0][1] = __builtin_amdgcn_mfma_f32_16x16x32_bf16(A.a0, B.b1, acc[0][1], 0, 0, 0);
    acc[0][2] = __builtin_amdgcn_mfma_f32_16x16x32_bf16(A.a0, B.b2, acc[0][2], 0, 0, 0);
    acc[0][3] = __builtin_amdgcn_mfma_f32_16x16x32_bf16(A.a0, B.b3, acc[0][3], 0, 0, 0);
    acc[1][0] = __builtin_amdgcn_mfma_f32_16x16x32_bf16(A.a1, B.b0, acc[1][0], 0, 0, 0);
    acc[1][1] = __builtin_amdgcn_mfma_f32_16x16x32_bf16(A.a1, B.b1, acc[1][1], 0, 0, 0);
    acc[1][2] = __builtin_amdgcn_mfma_f32_16x16x32_bf16(A.a1, B.b2, acc[1][2], 0, 0, 0);
    acc[1][3] = __builtin_amdgcn_mfma_f32_16x16x32_bf16(A.a1, B.b3, acc[1][3], 0, 0, 0);
    acc[2][0] = __builtin_amdgcn_mfma_f32_16x16x32_bf16(A.a2, B.b0, acc[2][0], 0, 0, 0);
    acc[2][1] = __builtin_amdgcn_mfma_f32_16x16x32_bf16(A.a2, B.b1, acc[2][1], 0, 0, 0);
    acc[2][2] = __builtin_amdgcn_mfma_f32_16x16x32_bf16(A.a2, B.b2, acc[2][2], 0, 0, 0);
    acc[2][3] = __builtin_amdgcn_mfma_f32_16x16x32_bf16(A.a2, B.b3, acc[2][3], 0, 0, 0);
    acc[3][0] = __builtin_amdgcn_mfma_f32_16x16x32_bf16(A.a3, B.b0, acc[3][0], 0, 0, 0);
    acc[3][1] = __builtin_amdgcn_mfma_f32_16x16x32_bf16(A.a3, B.b1, acc[3][1], 0, 0, 0);
    acc[3][2] = __builtin_amdgcn_mfma_f32_16x16x32_bf16(A.a3, B.b2, acc[3][2], 0, 0, 0);
    acc[3][3] = __builtin_amdgcn_mfma_f32_16x16x32_bf16(A.a3, B.b3, acc[3][3], 0, 0, 0);
    __builtin_amdgcn_s_setprio(0);
  };

  __syncthreads();                   // xs staged (drains B0/B1 loads too)

  Afrag A0, A1;
  ldA(0, A0);

  // 18 steps, fully unrolled: B rotation period 3 (2-ahead), A period 2 (1-ahead).
  #pragma unroll
  for (int it = 0; it < 3; ++it) {
    const int s = it * 6;
    loadB(s + 2, B2);  ldA(s + 1, A1);  mm(A0, B0);
    loadB(s + 3, B0);  ldA(s + 2, A0);  mm(A1, B1);
    loadB(s + 4, B1);  ldA(s + 3, A1);  mm(A0, B2);
    loadB(s + 5, B2);  ldA(s + 4, A0);  mm(A1, B0);
    loadB(s + 6, B0);  ldA(s + 5, A1);  mm(A0, B1);
    loadB(s + 7, B1);  ldA(s + 6, A0);  mm(A1, B2);
  }

  // ---- epilogue: bias + GELU in regs (all waves), then two 64-oc halves
  float bj[4];
  #pragma unroll
  for (int j = 0; j < 4; ++j) bj[j] = bias[wx * 64 + j * 16 + cl];

  #pragma unroll
  for (int i = 0; i < 4; ++i)
    #pragma unroll
    for (int j = 0; j < 4; ++j)
      #pragma unroll
      for (int r = 0; r < 4; ++r)
        acc[i][j][r] = gelu_f(acc[i][j][r] + bj[j]);

  __syncthreads();   // all xs reads done before tile overlays it

  #pragma unroll 1
  for (int half = 0; half < 2; ++half) {
    // acc -> tile for this oc half (oc half == wx by construction)
    if (wx == half) {
      #pragma unroll
      for (int i = 0; i < 4; ++i) {
        int owb = wy * 64 + i * 16 + q * 4;     // D row = ow = q*4+reg
        #pragma unroll
        for (int j = 0; j < 4; ++j)
          *(f32x4*)(tile + (j * 16 + cl) * TILE_STRIDE + owb) = acc[i][j];
      }
    }
    __syncthreads();

    // per-pixel group stats: 4 local groups x 128 ow
    #pragma unroll
    for (int s = tid; s < 4 * 128; s += 256) {
      int gl = s >> 7, ow = s & 127;
      const float* p = tile + (gl * 16) * TILE_STRIDE + ow;
      float sum = 0.f, s2 = 0.f;
      #pragma unroll
      for (int k = 0; k < 16; ++k) {
        float v = p[k * TILE_STRIDE];
        sum += v; s2 += v * v;
      }
      float mean = sum * (1.f / 16.f);
      float var  = s2 * (1.f / 16.f) - mean * mean;
      meanA[s] = mean;
      rstdA[s] = __builtin_amdgcn_rsqf(var + EPS);
    }
    __syncthreads();

    // normalize + affine + coalesced store (64 oc x 128 ow)
    #pragma unroll 4
    for (int it = 0; it < 8; ++it) {
      int idx = it * 256 + tid;
      int ow4 = (idx & 31) * 4;
      int ocl = idx >> 5;               // 0..63
      int oc  = half * 64 + ocl;
      int gl  = ocl >> 4;
      float gw = gnw[oc], gb = gnb[oc];
      f32x4 v  = *(const f32x4*)(tile + ocl * TILE_STRIDE + ow4);
      f32x4 m4 = *(const f32x4*)(meanA + gl * 128 + ow4);
      f32x4 r4 = *(const f32x4*)(rstdA + gl * 128 + ow4);
      f32x4 o;
      #pragma unroll
      for (int r = 0; r < 4; ++r) o[r] = (v[r] - m4[r]) * r4[r] * gw + gb;
      *(f32x4*)(out + ((n * 128 + oc) * 128 + oh) * 128 + ow4) = o;
    }
    if (half == 0) __syncthreads();   // tile/stats reads done before half 1 writes
  }
}

extern "C" void kernel_launch(void* const* d_in, const int* in_sizes, int n_in,
                              void* d_out, int out_size, void* d_ws, size_t ws_size,
                              hipStream_t stream) {
  const float* x   = (const float*)d_in[0];
  const float* w   = (const float*)d_in[1];
  const float* b   = (const float*)d_in[2];
  const float* gnw = (const float*)d_in[3];
  const float* gnb = (const float*)d_in[4];
  float* out = (float*)d_out;
  unsigned short* BT = (unsigned short*)d_ws;   // 18*128*32 bf16 = 147456 B

  prep_w<<<288, 256, 0, stream>>>(w, BT);
  conv_gelu_gn<<<dim3(128, 32), 256, 0, stream>>>(x, BT, b, gnw, gnb, out);
}